// Round 2
// baseline (2189.370 us; speedup 1.0000x reference)
//
#include <hip/hip_runtime.h>

#define T_LEN 4096
#define C_DIM 2048
#define REC 224          // packed record bytes: a16,b16,k16,r16,v16 bf16 + dec16 f32
#define CH 32            // scan steps per LDS chunk (32*224 = 7168 = 7 wave-loads)

typedef __attribute__((ext_vector_type(4))) float f32x4;
typedef __attribute__((ext_vector_type(8))) __bf16 bf16x8;
typedef __attribute__((ext_vector_type(8))) unsigned short u16x8;
typedef __attribute__((ext_vector_type(4))) unsigned int u32x4;
typedef __attribute__((ext_vector_type(2))) unsigned int u32x2;
typedef unsigned short u16;

typedef __attribute__((address_space(1))) const void* as1cv;
typedef __attribute__((address_space(3))) void* as3v;

__device__ __forceinline__ void gld16(const void* g, void* l) {
  __builtin_amdgcn_global_load_lds((as1cv)g, (as3v)l, 16, 0, 0);
}

__device__ __forceinline__ u16 f2bf(float f) {
  union { float f; unsigned u; } x; x.f = f;
  return (u16)((x.u + 0x7fffu + ((x.u >> 16) & 1u)) >> 16);
}
__device__ __forceinline__ float bflo(unsigned u) {
  union { unsigned u; float f; } x; x.u = u << 16; return x.f;
}
__device__ __forceinline__ float bfhi(unsigned u) {
  union { unsigned u; float f; } x; x.u = u & 0xffff0000u; return x.f;
}

// ---------------- weight fp32 -> bf16 ----------------
__global__ __launch_bounds__(256) void conv_bf16_k(const float* __restrict__ s,
                                                   u16* __restrict__ d, int n) {
  int i = (blockIdx.x * 256 + threadIdx.x) * 8;
  if (i >= n) return;
  f32x4 a = *(const f32x4*)(s + i);
  f32x4 b = *(const f32x4*)(s + i + 4);
  u16x8 o;
  o[0] = f2bf(a[0]); o[1] = f2bf(a[1]); o[2] = f2bf(a[2]); o[3] = f2bf(a[3]);
  o[4] = f2bf(b[0]); o[5] = f2bf(b[1]); o[6] = f2bf(b[2]); o[7] = f2bf(b[3]);
  *(u16x8*)(d + i) = o;
}

// ---------------- mix + LoRA down-projections ----------------
__global__ __launch_bounds__(256)
void mix_lora_k(const float* __restrict__ x,
                const float* __restrict__ xrw, const float* __restrict__ xww,
                const float* __restrict__ xkw, const float* __restrict__ xvw,
                const float* __restrict__ xaw, const float* __restrict__ xgw,
                const float* __restrict__ w1, const float* __restrict__ a1,
                const float* __restrict__ v1, const float* __restrict__ g1,
                u16* __restrict__ xr_bf, u16* __restrict__ xk_bf,
                u16* __restrict__ xv_bf, float* __restrict__ lora8) {
  const int rr = blockIdx.x;
  const int t = rr & (T_LEN - 1);
  const int tid = threadIdx.x;
  const int c0 = tid * 8;
  const float* xrow = x + (size_t)rr * C_DIM + c0;
  float xs[8] __attribute__((aligned(16)));
  float xp[8] __attribute__((aligned(16)));
  *(f32x4*)xs = *(const f32x4*)xrow;
  *(f32x4*)(xs + 4) = *(const f32x4*)(xrow + 4);
  if (t) {
    const float* pr = xrow - C_DIM;
    *(f32x4*)xp = *(const f32x4*)pr;
    *(f32x4*)(xp + 4) = *(const f32x4*)(pr + 4);
  } else {
    #pragma unroll
    for (int i = 0; i < 8; ++i) xp[i] = 0.f;
  }
  float wl[8], al[8], vl[8], gl[8];
  #pragma unroll
  for (int l = 0; l < 8; ++l) { wl[l] = 0.f; al[l] = 0.f; vl[l] = 0.f; gl[l] = 0.f; }
  u16x8 or_, ok_, ov_;
  #pragma unroll
  for (int ii = 0; ii < 8; ++ii) {
    int c = c0 + ii;
    float xi = xs[ii], dx = xp[ii] - xi;
    float xr_ = fmaf(dx, xrw[c], xi);
    float xw_ = fmaf(dx, xww[c], xi);
    float xk_ = fmaf(dx, xkw[c], xi);
    float xv_ = fmaf(dx, xvw[c], xi);
    float xa_ = fmaf(dx, xaw[c], xi);
    float xg_ = fmaf(dx, xgw[c], xi);
    or_[ii] = f2bf(xr_); ok_[ii] = f2bf(xk_); ov_[ii] = f2bf(xv_);
    #pragma unroll
    for (int l = 0; l < 8; ++l) {
      wl[l] = fmaf(xw_, w1[(size_t)c * 8 + l], wl[l]);
      al[l] = fmaf(xa_, a1[(size_t)c * 8 + l], al[l]);
      vl[l] = fmaf(xv_, v1[(size_t)c * 8 + l], vl[l]);
      gl[l] = fmaf(xg_, g1[(size_t)c * 8 + l], gl[l]);
    }
  }
  *(u16x8*)(xr_bf + (size_t)rr * C_DIM + c0) = or_;
  *(u16x8*)(xk_bf + (size_t)rr * C_DIM + c0) = ok_;
  *(u16x8*)(xv_bf + (size_t)rr * C_DIM + c0) = ov_;
  #pragma unroll
  for (int off = 1; off < 64; off <<= 1) {
    #pragma unroll
    for (int l = 0; l < 8; ++l) {
      wl[l] += __shfl_xor(wl[l], off);
      al[l] += __shfl_xor(al[l], off);
      vl[l] += __shfl_xor(vl[l], off);
      gl[l] += __shfl_xor(gl[l], off);
    }
  }
  __shared__ float red[4][32];
  const int wv = tid >> 6, ln = tid & 63;
  if (ln == 0) {
    #pragma unroll
    for (int l = 0; l < 8; ++l) {
      red[wv][l] = wl[l]; red[wv][8 + l] = al[l];
      red[wv][16 + l] = vl[l]; red[wv][24 + l] = gl[l];
    }
  }
  __syncthreads();
  if (tid < 32) {
    float s = red[0][tid] + red[1][tid] + red[2][tid] + red[3][tid];
    int mat = tid >> 3;
    if (mat == 0) s = tanhf(s);
    else if (mat == 3) s = 1.f / (1.f + expf(-s));
    lora8[(size_t)rr * 32 + tid] = s;
  }
}

// ---------------- bf16 MFMA GEMM: C[m,n] = sum_k A[m,k]*Bw[n,k] ----------------
// pmode 0: f32 row-major out (ld 2048). pmode 1: bf16 scatter into packed at poff.
__global__ __launch_bounds__(256)
void gemm_k(const u16* __restrict__ A, const u16* __restrict__ Bw,
            void* __restrict__ Co, int pmode, int poff) {
  __shared__ __attribute__((aligned(16))) u16 As[128 * 32];
  __shared__ __attribute__((aligned(16))) u16 Bs[128 * 32];
  const int tid = threadIdx.x;
  const int wv = tid >> 6, ln = tid & 63;
  const int wr = wv >> 1, wc = wv & 1;
  const int row0 = blockIdx.y * 128, col0 = blockIdx.x * 128;
  const int lr = ln & 15, lk = (ln >> 4) << 3;
  f32x4 acc[4][4];
  #pragma unroll
  for (int m = 0; m < 4; ++m)
    #pragma unroll
    for (int n = 0; n < 4; ++n) acc[m][n] = (f32x4){0.f, 0.f, 0.f, 0.f};
  const int e0 = tid * 8;
  const int r0 = e0 >> 5, kofs = e0 & 31;
  for (int kt = 0; kt < 2048; kt += 32) {
    __syncthreads();
    gld16(A + (size_t)(row0 + r0) * 2048 + kt + kofs, As + wv * 512);
    gld16(A + (size_t)(row0 + 64 + r0) * 2048 + kt + kofs, As + 2048 + wv * 512);
    gld16(Bw + (size_t)(col0 + r0) * 2048 + kt + kofs, Bs + wv * 512);
    gld16(Bw + (size_t)(col0 + 64 + r0) * 2048 + kt + kofs, Bs + 2048 + wv * 512);
    __syncthreads();
    bf16x8 af[4], bfr[4];
    #pragma unroll
    for (int m = 0; m < 4; ++m)
      af[m] = *(const bf16x8*)(As + (wr * 64 + m * 16 + lr) * 32 + lk);
    #pragma unroll
    for (int n = 0; n < 4; ++n)
      bfr[n] = *(const bf16x8*)(Bs + (wc * 64 + n * 16 + lr) * 32 + lk);
    #pragma unroll
    for (int m = 0; m < 4; ++m)
      #pragma unroll
      for (int n = 0; n < 4; ++n)
        acc[m][n] = __builtin_amdgcn_mfma_f32_16x16x32_bf16(af[m], bfr[n], acc[m][n], 0, 0, 0);
  }
  const int rowb = row0 + wr * 64 + ((ln >> 4) << 2);
  const int colb = col0 + wc * 64 + (ln & 15);
  #pragma unroll
  for (int m = 0; m < 4; ++m)
    #pragma unroll
    for (int n = 0; n < 4; ++n)
      #pragma unroll
      for (int qq = 0; qq < 4; ++qq) {
        int row = rowb + m * 16 + qq;
        int col = colb + n * 16;
        float val = acc[m][n][qq];
        if (pmode == 0) {
          ((float*)Co)[(size_t)row * 2048 + col] = val;
        } else {
          int bq = row >> 12, tq = row & (T_LEN - 1);
          int hq = col >> 4, jq = col & 15;
          *(u16*)((char*)Co + (size_t)((bq * 128 + hq) * T_LEN + tq) * REC
                  + poff + jq * 2) = f2bf(val);
        }
      }
}

// ---------------- post-GEMM: LoRA-up, decay, v-mix, kk-norm -> packed ----------------
__global__ __launch_bounds__(256)
void post_gemm_k(const float* __restrict__ v_first, const float* __restrict__ lora8,
                 const float* __restrict__ w0, const float* __restrict__ w2,
                 const float* __restrict__ a0, const float* __restrict__ a2,
                 const float* __restrict__ v0, const float* __restrict__ v2,
                 const float* __restrict__ k_k, const float* __restrict__ k_a,
                 char* __restrict__ packed) {
  const int rr = blockIdx.x;
  const int bq = rr >> 12, tq = rr & (T_LEN - 1);
  const int tid = threadIdx.x, c0 = tid * 8;
  const int hq = tid >> 1, j0 = (tid & 1) * 8;
  char* pb = packed + (size_t)((bq * 128 + hq) * T_LEN + tq) * REC;
  u32x4 uk = *(const u32x4*)(pb + 64 + j0 * 2);
  u32x4 uv = *(const u32x4*)(pb + 128 + j0 * 2);
  float kraw[8], vraw[8];
  float vf[8] __attribute__((aligned(16)));
  #pragma unroll
  for (int ii = 0; ii < 4; ++ii) {
    kraw[2 * ii] = bflo(uk[ii]); kraw[2 * ii + 1] = bfhi(uk[ii]);
    vraw[2 * ii] = bflo(uv[ii]); vraw[2 * ii + 1] = bfhi(uv[ii]);
  }
  const float* vfp = v_first + (size_t)rr * C_DIM + c0;
  *(f32x4*)vf = *(const f32x4*)vfp;
  *(f32x4*)(vf + 4) = *(const f32x4*)(vfp + 4);
  const float* lo = lora8 + (size_t)rr * 32;
  float w8[8] __attribute__((aligned(16)));
  float a8[8] __attribute__((aligned(16)));
  float v8[8] __attribute__((aligned(16)));
  *(f32x4*)w8 = *(const f32x4*)lo;        *(f32x4*)(w8 + 4) = *(const f32x4*)(lo + 4);
  *(f32x4*)a8 = *(const f32x4*)(lo + 8);  *(f32x4*)(a8 + 4) = *(const f32x4*)(lo + 12);
  *(f32x4*)v8 = *(const f32x4*)(lo + 16); *(f32x4*)(v8 + 4) = *(const f32x4*)(lo + 20);
  float kk[8], av[8];
  float dec[8] __attribute__((aligned(16)));
  u16x8 wk2, wv2;
  float ss = 0.f;
  #pragma unroll
  for (int ii = 0; ii < 8; ++ii) {
    int c = c0 + ii;
    float wr_ = w0[c], ar_ = a0[c], vr_ = v0[c];
    #pragma unroll
    for (int l = 0; l < 8; ++l) {
      wr_ = fmaf(w8[l], w2[(size_t)l * C_DIM + c], wr_);
      ar_ = fmaf(a8[l], a2[(size_t)l * C_DIM + c], ar_);
      vr_ = fmaf(v8[l], v2[(size_t)l * C_DIM + c], vr_);
    }
    float w_ = -log1pf(expf(-wr_)) - 0.5f;
    dec[ii] = expf(-expf(w_));
    float a_ = 1.f / (1.f + expf(-ar_));
    float vm = 1.f / (1.f + expf(-vr_));
    wv2[ii] = f2bf(fmaf(vf[ii] - vraw[ii], vm, vraw[ii]));
    kk[ii] = kraw[ii] * k_k[c];
    ss = fmaf(kk[ii], kk[ii], ss);
    av[ii] = a_;
    wk2[ii] = f2bf(kraw[ii] * fmaf(a_ - 1.f, k_a[c], 1.f));
  }
  ss += __shfl_xor(ss, 1);
  ss += __shfl_xor(ss, 2);
  ss += __shfl_xor(ss, 4);
  float sc = 1.f / fmaxf(sqrtf(ss), 1e-8f);
  u16x8 wa, wb2;
  #pragma unroll
  for (int ii = 0; ii < 8; ++ii) {
    float kn = kk[ii] * sc;
    wa[ii] = f2bf(-kn);
    wb2[ii] = f2bf(kn * av[ii]);
  }
  *(u16x8*)(pb + 0 + j0 * 2) = wa;
  *(u16x8*)(pb + 32 + j0 * 2) = wb2;
  *(u16x8*)(pb + 64 + j0 * 2) = wk2;
  *(u16x8*)(pb + 128 + j0 * 2) = wv2;
  *(f32x4*)(pb + 160 + j0 * 4) = *(f32x4*)dec;
  *(f32x4*)(pb + 176 + j0 * 4) = *(f32x4*)(dec + 4);
}

// ---------------- sequential RWKV7 scan: 1 head per wave; y overwrites dec slot ----------------
__global__ __launch_bounds__(64)
void scan_k(char* __restrict__ packed) {
  __shared__ __attribute__((aligned(16))) char buf[2][CH * REC];
  const int hb = blockIdx.x;
  const int lane = threadIdx.x;
  const int i = lane >> 2, q = lane & 3;
  char* src = packed + (size_t)hb * (T_LEN * REC);
  float S0 = 0.f, S1 = 0.f, S2 = 0.f, S3 = 0.f;
  #pragma unroll
  for (int j = 0; j < 7; ++j)
    gld16(src + j * 1024 + lane * 16, &buf[0][j * 1024]);
  const int NC = T_LEN / CH;
  for (int c = 0; c < NC; ++c) {
    asm volatile("s_waitcnt vmcnt(0)" ::: "memory");
    __syncthreads();
    if (c + 1 < NC) {
      char* s2 = src + (size_t)(c + 1) * (CH * REC);
      #pragma unroll
      for (int j = 0; j < 7; ++j)
        gld16(s2 + j * 1024 + lane * 16, &buf[(c + 1) & 1][j * 1024]);
    }
    const char* Bp = buf[c & 1];
    float* yg = (float*)(src + (size_t)c * (CH * REC) + 160);
    #pragma unroll 4
    for (int t = 0; t < CH; ++t) {
      const char* p = Bp + t * REC;
      u32x2 ua = *(const u32x2*)(p + q * 8);
      u32x2 ub = *(const u32x2*)(p + 32 + q * 8);
      u32x2 uk = *(const u32x2*)(p + 64 + q * 8);
      u32x2 ur = *(const u32x2*)(p + 96 + q * 8);
      unsigned uvv = *(const u16*)(p + 128 + i * 2);
      f32x4 dv = *(const f32x4*)(p + 160 + q * 16);
      float sa = S0 * bflo(ua[0]);
      sa = fmaf(S1, bfhi(ua[0]), sa);
      sa = fmaf(S2, bflo(ua[1]), sa);
      sa = fmaf(S3, bfhi(ua[1]), sa);
      sa += __shfl_xor(sa, 1);
      sa += __shfl_xor(sa, 2);
      float vvv = bflo(uvv);
      S0 = fmaf(S0, dv[0], fmaf(sa, bflo(ub[0]), vvv * bflo(uk[0])));
      S1 = fmaf(S1, dv[1], fmaf(sa, bfhi(ub[0]), vvv * bfhi(uk[0])));
      S2 = fmaf(S2, dv[2], fmaf(sa, bflo(ub[1]), vvv * bflo(uk[1])));
      S3 = fmaf(S3, dv[3], fmaf(sa, bfhi(ub[1]), vvv * bfhi(uk[1])));
      float yv = S0 * bflo(ur[0]);
      yv = fmaf(S1, bfhi(ur[0]), yv);
      yv = fmaf(S2, bflo(ur[1]), yv);
      yv = fmaf(S3, bfhi(ur[1]), yv);
      yv += __shfl_xor(yv, 1);
      yv += __shfl_xor(yv, 2);
      if (q == 0) yg[t * (REC / 4) + i] = yv;
    }
  }
}

// ---------------- GroupNorm + residual + gate -> bf16 ----------------
__global__ __launch_bounds__(256)
void post_gn_k(const char* __restrict__ packed, const float* __restrict__ lora8,
               const float* __restrict__ g2, const float* __restrict__ ln_g,
               const float* __restrict__ ln_b, const float* __restrict__ r_k,
               u16* __restrict__ og) {
  const int rr = blockIdx.x;
  const int bq = rr >> 12, tq = rr & (T_LEN - 1);
  const int tid = threadIdx.x, c0 = tid * 8;
  const int hq = tid >> 1, j0 = (tid & 1) * 8;
  const char* pb = packed + (size_t)((bq * 128 + hq) * T_LEN + tq) * REC;
  u32x4 uk = *(const u32x4*)(pb + 64 + j0 * 2);
  u32x4 ur = *(const u32x4*)(pb + 96 + j0 * 2);
  u32x4 uv = *(const u32x4*)(pb + 128 + j0 * 2);
  f32x4 y0 = *(const f32x4*)(pb + 160 + j0 * 4);
  f32x4 y1 = *(const f32x4*)(pb + 176 + j0 * 4);
  float o[8];
  o[0] = y0[0]; o[1] = y0[1]; o[2] = y0[2]; o[3] = y0[3];
  o[4] = y1[0]; o[5] = y1[1]; o[6] = y1[2]; o[7] = y1[3];
  float rv[8], kv[8], vv[8];
  #pragma unroll
  for (int ii = 0; ii < 4; ++ii) {
    kv[2 * ii] = bflo(uk[ii]); kv[2 * ii + 1] = bfhi(uk[ii]);
    rv[2 * ii] = bflo(ur[ii]); rv[2 * ii + 1] = bfhi(ur[ii]);
    vv[2 * ii] = bflo(uv[ii]); vv[2 * ii + 1] = bfhi(uv[ii]);
  }
  float g8[8] __attribute__((aligned(16)));
  const float* lo = lora8 + (size_t)rr * 32 + 24;
  *(f32x4*)g8 = *(const f32x4*)lo;
  *(f32x4*)(g8 + 4) = *(const f32x4*)(lo + 4);
  float s1 = 0.f, s2 = 0.f, srk = 0.f;
  #pragma unroll
  for (int ii = 0; ii < 8; ++ii) {
    s1 += o[ii];
    s2 = fmaf(o[ii], o[ii], s2);
    srk = fmaf(rv[ii] * kv[ii], r_k[c0 + ii], srk);
  }
  s1 += __shfl_xor(s1, 1); s1 += __shfl_xor(s1, 2); s1 += __shfl_xor(s1, 4);
  s2 += __shfl_xor(s2, 1); s2 += __shfl_xor(s2, 2); s2 += __shfl_xor(s2, 4);
  srk += __shfl_xor(srk, 1); srk += __shfl_xor(srk, 2); srk += __shfl_xor(srk, 4);
  float mu = s1 * (1.f / 64.f);
  float var = s2 * (1.f / 64.f) - mu * mu;
  float rstd = rsqrtf(var + 0.00064f);
  u16x8 ov;
  #pragma unroll
  for (int ii = 0; ii < 8; ++ii) {
    int c = c0 + ii;
    float on = fmaf((o[ii] - mu) * rstd, ln_g[c], ln_b[c]);
    float o2 = fmaf(srk, vv[ii], on);
    float gg = 0.f;
    #pragma unroll
    for (int l = 0; l < 8; ++l) gg = fmaf(g8[l], g2[(size_t)l * C_DIM + c], gg);
    ov[ii] = f2bf(o2 * gg);
  }
  *(u16x8*)(og + (size_t)rr * C_DIM + c0) = ov;
}

extern "C" void kernel_launch(void* const* d_in, const int* in_sizes, int n_in,
                              void* d_out, int out_size, void* d_ws, size_t ws_size,
                              hipStream_t stream) {
  (void)in_sizes; (void)n_in; (void)out_size;
  const float* x      = (const float*)d_in[0];
  const float* v_first= (const float*)d_in[1];
  const float* x_r    = (const float*)d_in[2];
  const float* x_w    = (const float*)d_in[3];
  const float* x_k    = (const float*)d_in[4];
  const float* x_v    = (const float*)d_in[5];
  const float* x_a    = (const float*)d_in[6];
  const float* x_g    = (const float*)d_in[7];
  const float* w0     = (const float*)d_in[8];
  const float* w1     = (const float*)d_in[9];
  const float* w2     = (const float*)d_in[10];
  const float* a0     = (const float*)d_in[11];
  const float* a1     = (const float*)d_in[12];
  const float* a2     = (const float*)d_in[13];
  const float* v0     = (const float*)d_in[14];
  const float* v1     = (const float*)d_in[15];
  const float* v2     = (const float*)d_in[16];
  const float* g1     = (const float*)d_in[17];
  const float* g2     = (const float*)d_in[18];
  const float* k_k    = (const float*)d_in[19];
  const float* k_a    = (const float*)d_in[20];
  const float* r_k    = (const float*)d_in[21];
  const float* Wr     = (const float*)d_in[22];
  const float* Wk     = (const float*)d_in[23];
  const float* Wv     = (const float*)d_in[24];
  const float* Wo     = (const float*)d_in[25];
  const float* ln_g   = (const float*)d_in[26];
  const float* ln_b   = (const float*)d_in[27];

  // workspace layout (total 370,147,328 B)
  if (ws_size < 370147328ull) return;   // diagnostic: leaves output untouched
  char* ws = (char*)d_ws;
  u16* Wr_bf = (u16*)(ws + 0);            //  8 MB each
  u16* Wk_bf = Wr_bf + 4194304;
  u16* Wv_bf = Wk_bf + 4194304;
  u16* Wo_bf = Wv_bf + 4194304;
  u16* xr_bf = (u16*)(ws + 33554432);     // 32 MB each
  u16* xk_bf = xr_bf + 16777216;
  u16* xv_bf = xk_bf + 16777216;
  float* lora8 = (float*)(ws + 134217728); // 1 MB
  char* packed = ws + 135266304;           // 224 MB
  u16* og = xr_bf;                         // reuse (dead after r-GEMM)
  float* out = (float*)d_out;

  conv_bf16_k<<<2048, 256, 0, stream>>>(Wr, Wr_bf, 4194304);
  conv_bf16_k<<<2048, 256, 0, stream>>>(Wk, Wk_bf, 4194304);
  conv_bf16_k<<<2048, 256, 0, stream>>>(Wv, Wv_bf, 4194304);
  conv_bf16_k<<<2048, 256, 0, stream>>>(Wo, Wo_bf, 4194304);

  mix_lora_k<<<8192, 256, 0, stream>>>(x, x_r, x_w, x_k, x_v, x_a, x_g,
                                       w1, a1, v1, g1, xr_bf, xk_bf, xv_bf, lora8);

  dim3 gg(16, 64);
  gemm_k<<<gg, 256, 0, stream>>>(xr_bf, Wr_bf, packed, 1, 96);   // r -> @96
  gemm_k<<<gg, 256, 0, stream>>>(xk_bf, Wk_bf, packed, 1, 64);   // k -> @64
  gemm_k<<<gg, 256, 0, stream>>>(xv_bf, Wv_bf, packed, 1, 128);  // v -> @128

  post_gemm_k<<<8192, 256, 0, stream>>>(v_first, lora8, w0, w2, a0, a2, v0, v2,
                                        k_k, k_a, packed);

  scan_k<<<256, 64, 0, stream>>>(packed);

  post_gn_k<<<8192, 256, 0, stream>>>(packed, lora8, g2, ln_g, ln_b, r_k, og);

  gemm_k<<<gg, 256, 0, stream>>>(og, Wo_bf, out, 0, 0);

  hipMemcpyAsync(out + 16777216, v_first, (size_t)16777216 * 4,
                 hipMemcpyDeviceToDevice, stream);
}

// Round 3
// 1811.847 us; speedup vs baseline: 1.2084x; 1.2084x over previous
//
#include <hip/hip_runtime.h>

#define T_LEN 4096
#define C_DIM 2048
#define REC 224          // packed record: [a|b]x4 quads 64B, [k|r]x4 quads 64B, v 32B, dec/y 64B
#define CH 64            // scan steps per LDS chunk (64*224 = 14336 = 14 wave-loads)

typedef __attribute__((ext_vector_type(4))) float f32x4;
typedef __attribute__((ext_vector_type(8))) __bf16 bf16x8;
typedef __attribute__((ext_vector_type(8))) unsigned short u16x8;
typedef __attribute__((ext_vector_type(4))) unsigned int u32x4;
typedef __attribute__((ext_vector_type(2))) unsigned int u32x2;
typedef unsigned short u16;

typedef __attribute__((address_space(1))) const void* as1cv;
typedef __attribute__((address_space(3))) void* as3v;

__device__ __forceinline__ void gld16(const void* g, void* l) {
  __builtin_amdgcn_global_load_lds((as1cv)g, (as3v)l, 16, 0, 0);
}

__device__ __forceinline__ u16 f2bf(float f) {
  union { float f; unsigned u; } x; x.f = f;
  return (u16)((x.u + 0x7fffu + ((x.u >> 16) & 1u)) >> 16);
}
__device__ __forceinline__ float bflo(unsigned u) {
  union { unsigned u; float f; } x; x.u = u << 16; return x.f;
}
__device__ __forceinline__ float bfhi(unsigned u) {
  union { unsigned u; float f; } x; x.u = u & 0xffff0000u; return x.f;
}
// sum over the 4 lanes of a quad via DPP quad_perm (VALU latency, no LDS pipe)
__device__ __forceinline__ float quad_sum(float x) {
  int a = __builtin_bit_cast(int, x);
  int b = __builtin_amdgcn_update_dpp(0, a, 0xB1, 0xF, 0xF, true);  // xor 1
  float y = x + __builtin_bit_cast(float, b);
  int c = __builtin_bit_cast(int, y);
  int d = __builtin_amdgcn_update_dpp(0, c, 0x4E, 0xF, 0xF, true);  // xor 2
  return y + __builtin_bit_cast(float, d);
}

// ---------------- weights fp32 -> bf16 (all four in one launch) ----------------
__global__ __launch_bounds__(256)
void conv_bf16_k(const float* __restrict__ s0, const float* __restrict__ s1,
                 const float* __restrict__ s2, const float* __restrict__ s3,
                 u16* __restrict__ d0) {
  const float* s = (blockIdx.y == 0) ? s0 : (blockIdx.y == 1) ? s1
                   : (blockIdx.y == 2) ? s2 : s3;
  u16* d = d0 + (size_t)blockIdx.y * 4194304;
  int i = (blockIdx.x * 256 + threadIdx.x) * 8;
  f32x4 a = *(const f32x4*)(s + i);
  f32x4 b = *(const f32x4*)(s + i + 4);
  u16x8 o;
  o[0] = f2bf(a[0]); o[1] = f2bf(a[1]); o[2] = f2bf(a[2]); o[3] = f2bf(a[3]);
  o[4] = f2bf(b[0]); o[5] = f2bf(b[1]); o[6] = f2bf(b[2]); o[7] = f2bf(b[3]);
  *(u16x8*)(d + i) = o;
}

// ---------------- mix + LoRA down-projections ----------------
__global__ __launch_bounds__(256)
void mix_lora_k(const float* __restrict__ x,
                const float* __restrict__ xrw, const float* __restrict__ xww,
                const float* __restrict__ xkw, const float* __restrict__ xvw,
                const float* __restrict__ xaw, const float* __restrict__ xgw,
                const float* __restrict__ w1, const float* __restrict__ a1,
                const float* __restrict__ v1, const float* __restrict__ g1,
                u16* __restrict__ xr_bf, u16* __restrict__ xk_bf,
                u16* __restrict__ xv_bf, float* __restrict__ lora8) {
  const int rr = blockIdx.x;
  const int t = rr & (T_LEN - 1);
  const int tid = threadIdx.x;
  const int c0 = tid * 8;
  const float* xrow = x + (size_t)rr * C_DIM + c0;
  float xs[8] __attribute__((aligned(16)));
  float xp[8] __attribute__((aligned(16)));
  *(f32x4*)xs = *(const f32x4*)xrow;
  *(f32x4*)(xs + 4) = *(const f32x4*)(xrow + 4);
  if (t) {
    const float* pr = xrow - C_DIM;
    *(f32x4*)xp = *(const f32x4*)pr;
    *(f32x4*)(xp + 4) = *(const f32x4*)(pr + 4);
  } else {
    #pragma unroll
    for (int i = 0; i < 8; ++i) xp[i] = 0.f;
  }
  float wl[8], al[8], vl[8], gl[8];
  #pragma unroll
  for (int l = 0; l < 8; ++l) { wl[l] = 0.f; al[l] = 0.f; vl[l] = 0.f; gl[l] = 0.f; }
  u16x8 or_, ok_, ov_;
  #pragma unroll
  for (int ii = 0; ii < 8; ++ii) {
    int c = c0 + ii;
    float xi = xs[ii], dx = xp[ii] - xi;
    float xr_ = fmaf(dx, xrw[c], xi);
    float xw_ = fmaf(dx, xww[c], xi);
    float xk_ = fmaf(dx, xkw[c], xi);
    float xv_ = fmaf(dx, xvw[c], xi);
    float xa_ = fmaf(dx, xaw[c], xi);
    float xg_ = fmaf(dx, xgw[c], xi);
    or_[ii] = f2bf(xr_); ok_[ii] = f2bf(xk_); ov_[ii] = f2bf(xv_);
    #pragma unroll
    for (int l = 0; l < 8; ++l) {
      wl[l] = fmaf(xw_, w1[(size_t)c * 8 + l], wl[l]);
      al[l] = fmaf(xa_, a1[(size_t)c * 8 + l], al[l]);
      vl[l] = fmaf(xv_, v1[(size_t)c * 8 + l], vl[l]);
      gl[l] = fmaf(xg_, g1[(size_t)c * 8 + l], gl[l]);
    }
  }
  *(u16x8*)(xr_bf + (size_t)rr * C_DIM + c0) = or_;
  *(u16x8*)(xk_bf + (size_t)rr * C_DIM + c0) = ok_;
  *(u16x8*)(xv_bf + (size_t)rr * C_DIM + c0) = ov_;
  #pragma unroll
  for (int off = 1; off < 64; off <<= 1) {
    #pragma unroll
    for (int l = 0; l < 8; ++l) {
      wl[l] += __shfl_xor(wl[l], off);
      al[l] += __shfl_xor(al[l], off);
      vl[l] += __shfl_xor(vl[l], off);
      gl[l] += __shfl_xor(gl[l], off);
    }
  }
  __shared__ float red[4][32];
  const int wv = tid >> 6, ln = tid & 63;
  if (ln == 0) {
    #pragma unroll
    for (int l = 0; l < 8; ++l) {
      red[wv][l] = wl[l]; red[wv][8 + l] = al[l];
      red[wv][16 + l] = vl[l]; red[wv][24 + l] = gl[l];
    }
  }
  __syncthreads();
  if (tid < 32) {
    float s = red[0][tid] + red[1][tid] + red[2][tid] + red[3][tid];
    int mat = tid >> 3;
    if (mat == 0) s = tanhf(s);
    else if (mat == 3) s = 1.f / (1.f + expf(-s));
    lora8[(size_t)rr * 32 + tid] = s;
  }
}

// ---------------- bf16 MFMA GEMM: C[m,n] = sum_k A[m,k]*Bw[n,k] ----------------
// pmode 0: f32 row-major out. pmode 1: bf16 scatter into packed record
//   (inter=1: quad-interleaved slot at sbase; inter=0: contiguous at sbase).
__global__ __launch_bounds__(256)
void gemm_k(const u16* __restrict__ A, const u16* __restrict__ Bw,
            void* __restrict__ Co, int pmode, int sbase, int inter) {
  __shared__ __attribute__((aligned(16))) u16 As[128 * 32];
  __shared__ __attribute__((aligned(16))) u16 Bs[128 * 32];
  const int tid = threadIdx.x;
  const int wv = tid >> 6, ln = tid & 63;
  const int wr = wv >> 1, wc = wv & 1;
  const int row0 = blockIdx.y * 128, col0 = blockIdx.x * 128;
  const int lr = ln & 15, lk = (ln >> 4) << 3;
  f32x4 acc[4][4];
  #pragma unroll
  for (int m = 0; m < 4; ++m)
    #pragma unroll
    for (int n = 0; n < 4; ++n) acc[m][n] = (f32x4){0.f, 0.f, 0.f, 0.f};
  const int e0 = tid * 8;
  const int r0 = e0 >> 5, kofs = e0 & 31;
  for (int kt = 0; kt < 2048; kt += 32) {
    __syncthreads();
    gld16(A + (size_t)(row0 + r0) * 2048 + kt + kofs, As + wv * 512);
    gld16(A + (size_t)(row0 + 64 + r0) * 2048 + kt + kofs, As + 2048 + wv * 512);
    gld16(Bw + (size_t)(col0 + r0) * 2048 + kt + kofs, Bs + wv * 512);
    gld16(Bw + (size_t)(col0 + 64 + r0) * 2048 + kt + kofs, Bs + 2048 + wv * 512);
    __syncthreads();
    bf16x8 af[4], bfr[4];
    #pragma unroll
    for (int m = 0; m < 4; ++m)
      af[m] = *(const bf16x8*)(As + (wr * 64 + m * 16 + lr) * 32 + lk);
    #pragma unroll
    for (int n = 0; n < 4; ++n)
      bfr[n] = *(const bf16x8*)(Bs + (wc * 64 + n * 16 + lr) * 32 + lk);
    #pragma unroll
    for (int m = 0; m < 4; ++m)
      #pragma unroll
      for (int n = 0; n < 4; ++n)
        acc[m][n] = __builtin_amdgcn_mfma_f32_16x16x32_bf16(af[m], bfr[n], acc[m][n], 0, 0, 0);
  }
  const int rowb = row0 + wr * 64 + ((ln >> 4) << 2);
  const int colb = col0 + wc * 64 + (ln & 15);
  #pragma unroll
  for (int m = 0; m < 4; ++m)
    #pragma unroll
    for (int n = 0; n < 4; ++n)
      #pragma unroll
      for (int qq = 0; qq < 4; ++qq) {
        int row = rowb + m * 16 + qq;
        int col = colb + n * 16;
        float val = acc[m][n][qq];
        if (pmode == 0) {
          ((float*)Co)[(size_t)row * 2048 + col] = val;
        } else {
          int bq = row >> 12, tq = row & (T_LEN - 1);
          int hq = col >> 4, jq = col & 15;
          int off = inter ? (sbase + 16 * (jq >> 2) + 2 * (jq & 3))
                          : (sbase + 2 * jq);
          *(u16*)((char*)Co + (size_t)((bq * 128 + hq) * T_LEN + tq) * REC + off)
              = f2bf(val);
        }
      }
}

// ---------------- post-GEMM: LoRA-up, decay, v-mix, kk-norm -> packed ----------------
__global__ __launch_bounds__(256)
void post_gemm_k(const float* __restrict__ v_first, const float* __restrict__ lora8,
                 const float* __restrict__ w0, const float* __restrict__ w2,
                 const float* __restrict__ a0, const float* __restrict__ a2,
                 const float* __restrict__ v0, const float* __restrict__ v2,
                 const float* __restrict__ k_k, const float* __restrict__ k_a,
                 char* __restrict__ packed) {
  const int rr = blockIdx.x;
  const int bq = rr >> 12, tq = rr & (T_LEN - 1);
  const int tid = threadIdx.x, c0 = tid * 8;
  const int hq = tid >> 1, j0 = (tid & 1) * 8, q0 = (tid & 1) * 2;
  char* pb = packed + (size_t)((bq * 128 + hq) * T_LEN + tq) * REC;
  u32x2 uk0 = *(const u32x2*)(pb + 64 + 16 * q0);
  u32x2 uk1 = *(const u32x2*)(pb + 64 + 16 * q0 + 16);
  u32x4 uv = *(const u32x4*)(pb + 128 + 2 * j0);
  float kraw[8], vraw[8];
  kraw[0] = bflo(uk0[0]); kraw[1] = bfhi(uk0[0]);
  kraw[2] = bflo(uk0[1]); kraw[3] = bfhi(uk0[1]);
  kraw[4] = bflo(uk1[0]); kraw[5] = bfhi(uk1[0]);
  kraw[6] = bflo(uk1[1]); kraw[7] = bfhi(uk1[1]);
  #pragma unroll
  for (int ii = 0; ii < 4; ++ii) {
    vraw[2 * ii] = bflo(uv[ii]); vraw[2 * ii + 1] = bfhi(uv[ii]);
  }
  float vf[8] __attribute__((aligned(16)));
  const float* vfp = v_first + (size_t)rr * C_DIM + c0;
  *(f32x4*)vf = *(const f32x4*)vfp;
  *(f32x4*)(vf + 4) = *(const f32x4*)(vfp + 4);
  const float* lo = lora8 + (size_t)rr * 32;
  float w8[8] __attribute__((aligned(16)));
  float a8[8] __attribute__((aligned(16)));
  float v8[8] __attribute__((aligned(16)));
  *(f32x4*)w8 = *(const f32x4*)lo;        *(f32x4*)(w8 + 4) = *(const f32x4*)(lo + 4);
  *(f32x4*)a8 = *(const f32x4*)(lo + 8);  *(f32x4*)(a8 + 4) = *(const f32x4*)(lo + 12);
  *(f32x4*)v8 = *(const f32x4*)(lo + 16); *(f32x4*)(v8 + 4) = *(const f32x4*)(lo + 20);
  float kk[8], av[8];
  float dec[8] __attribute__((aligned(16)));
  u16 wk[8] __attribute__((aligned(8)));
  u16x8 wv2;
  float ss = 0.f;
  #pragma unroll
  for (int ii = 0; ii < 8; ++ii) {
    int c = c0 + ii;
    float wr_ = w0[c], ar_ = a0[c], vr_ = v0[c];
    #pragma unroll
    for (int l = 0; l < 8; ++l) {
      wr_ = fmaf(w8[l], w2[(size_t)l * C_DIM + c], wr_);
      ar_ = fmaf(a8[l], a2[(size_t)l * C_DIM + c], ar_);
      vr_ = fmaf(v8[l], v2[(size_t)l * C_DIM + c], vr_);
    }
    float w_ = -log1pf(expf(-wr_)) - 0.5f;
    dec[ii] = expf(-expf(w_));
    float a_ = 1.f / (1.f + expf(-ar_));
    float vm = 1.f / (1.f + expf(-vr_));
    wv2[ii] = f2bf(fmaf(vf[ii] - vraw[ii], vm, vraw[ii]));
    kk[ii] = kraw[ii] * k_k[c];
    ss = fmaf(kk[ii], kk[ii], ss);
    av[ii] = a_;
    wk[ii] = f2bf(kraw[ii] * fmaf(a_ - 1.f, k_a[c], 1.f));
  }
  ss += __shfl_xor(ss, 1);
  ss += __shfl_xor(ss, 2);
  ss += __shfl_xor(ss, 4);
  float sc = 1.f / fmaxf(sqrtf(ss), 1e-8f);
  u16 wa[8] __attribute__((aligned(8)));
  u16 wb[8] __attribute__((aligned(8)));
  #pragma unroll
  for (int ii = 0; ii < 8; ++ii) {
    float kn = kk[ii] * sc;
    wa[ii] = f2bf(-kn);
    wb[ii] = f2bf(kn * av[ii]);
  }
  // a/b quad-interleaved
  *(u32x2*)(pb + 16 * q0) = *(u32x2*)&wa[0];
  *(u32x2*)(pb + 16 * q0 + 16) = *(u32x2*)&wa[4];
  *(u32x2*)(pb + 16 * q0 + 8) = *(u32x2*)&wb[0];
  *(u32x2*)(pb + 16 * q0 + 24) = *(u32x2*)&wb[4];
  // k quad-interleaved (r slots untouched)
  *(u32x2*)(pb + 64 + 16 * q0) = *(u32x2*)&wk[0];
  *(u32x2*)(pb + 64 + 16 * q0 + 16) = *(u32x2*)&wk[4];
  // v contiguous
  *(u16x8*)(pb + 128 + 2 * j0) = wv2;
  // dec f32
  *(f32x4*)(pb + 160 + 4 * j0) = *(f32x4*)dec;
  *(f32x4*)(pb + 160 + 4 * j0 + 16) = *(f32x4*)(dec + 4);
}

// ---------------- sequential RWKV7 scan: 1 head per wave; y overwrites dec slot ----------------
__global__ __launch_bounds__(64)
void scan_k(char* __restrict__ packed) {
  __shared__ __attribute__((aligned(16))) char buf[2][CH * REC];
  const int hb = blockIdx.x;
  const int lane = threadIdx.x;
  const int i = lane >> 2, q = lane & 3;
  char* src = packed + (size_t)hb * (T_LEN * REC);
  float S0 = 0.f, S1 = 0.f, S2 = 0.f, S3 = 0.f;
  #pragma unroll
  for (int j = 0; j < 14; ++j)
    gld16(src + j * 1024 + lane * 16, &buf[0][j * 1024]);
  const int NC = T_LEN / CH;
  for (int c = 0; c < NC; ++c) {
    asm volatile("s_waitcnt vmcnt(0)" ::: "memory");
    __syncthreads();
    if (c + 1 < NC) {
      char* s2 = src + (size_t)(c + 1) * (CH * REC);
      #pragma unroll
      for (int j = 0; j < 14; ++j)
        gld16(s2 + j * 1024 + lane * 16, &buf[(c + 1) & 1][j * 1024]);
    }
    const char* Bp = buf[c & 1];
    float* yg = (float*)(src + (size_t)c * (CH * REC) + 160);
    #pragma unroll 4
    for (int t = 0; t < CH; ++t) {
      const char* p = Bp + t * REC;
      u32x4 uab = *(const u32x4*)(p + q * 16);        // a0a1 a2a3 b0b1 b2b3
      u32x4 ukr = *(const u32x4*)(p + 64 + q * 16);   // k0k1 k2k3 r0r1 r2r3
      unsigned uvv = *(const u16*)(p + 128 + i * 2);
      f32x4 dv = *(const f32x4*)(p + 160 + q * 16);
      float t0 = S0 * bflo(uab[0]);
      float t1 = S2 * bflo(uab[1]);
      t0 = fmaf(S1, bfhi(uab[0]), t0);
      t1 = fmaf(S3, bfhi(uab[1]), t1);
      float sa = quad_sum(t0 + t1);
      float vvv = bflo(uvv);
      S0 = fmaf(S0, dv[0], fmaf(sa, bflo(uab[2]), vvv * bflo(ukr[0])));
      S1 = fmaf(S1, dv[1], fmaf(sa, bfhi(uab[2]), vvv * bfhi(ukr[0])));
      S2 = fmaf(S2, dv[2], fmaf(sa, bflo(uab[3]), vvv * bflo(ukr[1])));
      S3 = fmaf(S3, dv[3], fmaf(sa, bfhi(uab[3]), vvv * bfhi(ukr[1])));
      float y0 = S0 * bflo(ukr[2]);
      float y1 = S2 * bflo(ukr[3]);
      y0 = fmaf(S1, bfhi(ukr[2]), y0);
      y1 = fmaf(S3, bfhi(ukr[3]), y1);
      float yv = quad_sum(y0 + y1);
      if (q == 0) yg[t * (REC / 4) + i] = yv;
    }
  }
}

// ---------------- GroupNorm + residual + gate -> bf16 ----------------
__global__ __launch_bounds__(256)
void post_gn_k(const char* __restrict__ packed, const float* __restrict__ lora8,
               const float* __restrict__ g2, const float* __restrict__ ln_g,
               const float* __restrict__ ln_b, const float* __restrict__ r_k,
               u16* __restrict__ og) {
  const int rr = blockIdx.x;
  const int bq = rr >> 12, tq = rr & (T_LEN - 1);
  const int tid = threadIdx.x, c0 = tid * 8;
  const int hq = tid >> 1, j0 = (tid & 1) * 8, q0 = (tid & 1) * 2;
  const char* pb = packed + (size_t)((bq * 128 + hq) * T_LEN + tq) * REC;
  u32x4 ukr0 = *(const u32x4*)(pb + 64 + 16 * q0);        // k0..k3 r0..r3
  u32x4 ukr1 = *(const u32x4*)(pb + 64 + 16 * q0 + 16);   // k4..k7 r4..r7
  u32x4 uv = *(const u32x4*)(pb + 128 + 2 * j0);
  f32x4 y0 = *(const f32x4*)(pb + 160 + 4 * j0);
  f32x4 y1 = *(const f32x4*)(pb + 160 + 4 * j0 + 16);
  float o[8];
  o[0] = y0[0]; o[1] = y0[1]; o[2] = y0[2]; o[3] = y0[3];
  o[4] = y1[0]; o[5] = y1[1]; o[6] = y1[2]; o[7] = y1[3];
  float rv[8], kv[8], vv[8];
  kv[0] = bflo(ukr0[0]); kv[1] = bfhi(ukr0[0]); kv[2] = bflo(ukr0[1]); kv[3] = bfhi(ukr0[1]);
  rv[0] = bflo(ukr0[2]); rv[1] = bfhi(ukr0[2]); rv[2] = bflo(ukr0[3]); rv[3] = bfhi(ukr0[3]);
  kv[4] = bflo(ukr1[0]); kv[5] = bfhi(ukr1[0]); kv[6] = bflo(ukr1[1]); kv[7] = bfhi(ukr1[1]);
  rv[4] = bflo(ukr1[2]); rv[5] = bfhi(ukr1[2]); rv[6] = bflo(ukr1[3]); rv[7] = bfhi(ukr1[3]);
  #pragma unroll
  for (int ii = 0; ii < 4; ++ii) {
    vv[2 * ii] = bflo(uv[ii]); vv[2 * ii + 1] = bfhi(uv[ii]);
  }
  float g8[8] __attribute__((aligned(16)));
  const float* lo = lora8 + (size_t)rr * 32 + 24;
  *(f32x4*)g8 = *(const f32x4*)lo;
  *(f32x4*)(g8 + 4) = *(const f32x4*)(lo + 4);
  float s1 = 0.f, s2 = 0.f, srk = 0.f;
  #pragma unroll
  for (int ii = 0; ii < 8; ++ii) {
    s1 += o[ii];
    s2 = fmaf(o[ii], o[ii], s2);
    srk = fmaf(rv[ii] * kv[ii], r_k[c0 + ii], srk);
  }
  s1 += __shfl_xor(s1, 1); s1 += __shfl_xor(s1, 2); s1 += __shfl_xor(s1, 4);
  s2 += __shfl_xor(s2, 1); s2 += __shfl_xor(s2, 2); s2 += __shfl_xor(s2, 4);
  srk += __shfl_xor(srk, 1); srk += __shfl_xor(srk, 2); srk += __shfl_xor(srk, 4);
  float mu = s1 * (1.f / 64.f);
  float var = s2 * (1.f / 64.f) - mu * mu;
  float rstd = rsqrtf(var + 0.00064f);
  u16x8 ov;
  #pragma unroll
  for (int ii = 0; ii < 8; ++ii) {
    int c = c0 + ii;
    float on = fmaf((o[ii] - mu) * rstd, ln_g[c], ln_b[c]);
    float o2 = fmaf(srk, vv[ii], on);
    float gg = 0.f;
    #pragma unroll
    for (int l = 0; l < 8; ++l) gg = fmaf(g8[l], g2[(size_t)l * C_DIM + c], gg);
    ov[ii] = f2bf(o2 * gg);
  }
  *(u16x8*)(og + (size_t)rr * C_DIM + c0) = ov;
}

extern "C" void kernel_launch(void* const* d_in, const int* in_sizes, int n_in,
                              void* d_out, int out_size, void* d_ws, size_t ws_size,
                              hipStream_t stream) {
  (void)in_sizes; (void)n_in; (void)out_size;
  const float* x      = (const float*)d_in[0];
  const float* v_first= (const float*)d_in[1];
  const float* x_r    = (const float*)d_in[2];
  const float* x_w    = (const float*)d_in[3];
  const float* x_k    = (const float*)d_in[4];
  const float* x_v    = (const float*)d_in[5];
  const float* x_a    = (const float*)d_in[6];
  const float* x_g    = (const float*)d_in[7];
  const float* w0     = (const float*)d_in[8];
  const float* w1     = (const float*)d_in[9];
  const float* w2     = (const float*)d_in[10];
  const float* a0     = (const float*)d_in[11];
  const float* a1     = (const float*)d_in[12];
  const float* a2     = (const float*)d_in[13];
  const float* v0     = (const float*)d_in[14];
  const float* v1     = (const float*)d_in[15];
  const float* v2     = (const float*)d_in[16];
  const float* g1     = (const float*)d_in[17];
  const float* g2     = (const float*)d_in[18];
  const float* k_k    = (const float*)d_in[19];
  const float* k_a    = (const float*)d_in[20];
  const float* r_k    = (const float*)d_in[21];
  const float* Wr     = (const float*)d_in[22];
  const float* Wk     = (const float*)d_in[23];
  const float* Wv     = (const float*)d_in[24];
  const float* Wo     = (const float*)d_in[25];
  const float* ln_g   = (const float*)d_in[26];
  const float* ln_b   = (const float*)d_in[27];

  if (ws_size < 370147328ull) return;
  char* ws = (char*)d_ws;
  u16* Wr_bf = (u16*)(ws + 0);            //  8 MB each, contiguous (conv indexes)
  u16* Wk_bf = Wr_bf + 4194304;
  u16* Wv_bf = Wk_bf + 4194304;
  u16* Wo_bf = Wv_bf + 4194304;
  u16* xr_bf = (u16*)(ws + 33554432);     // 32 MB each
  u16* xk_bf = xr_bf + 16777216;
  u16* xv_bf = xk_bf + 16777216;
  float* lora8 = (float*)(ws + 134217728); // 1 MB
  char* packed = ws + 135266304;           // 224 MB
  u16* og = xr_bf;                         // reuse (dead after r-GEMM)
  float* out = (float*)d_out;

  conv_bf16_k<<<dim3(2048, 4), 256, 0, stream>>>(Wr, Wk, Wv, Wo, Wr_bf);

  mix_lora_k<<<8192, 256, 0, stream>>>(x, x_r, x_w, x_k, x_v, x_a, x_g,
                                       w1, a1, v1, g1, xr_bf, xk_bf, xv_bf, lora8);

  dim3 gg(16, 64);
  gemm_k<<<gg, 256, 0, stream>>>(xk_bf, Wk_bf, packed, 1, 64, 1);   // k quads
  gemm_k<<<gg, 256, 0, stream>>>(xr_bf, Wr_bf, packed, 1, 72, 1);   // r quads
  gemm_k<<<gg, 256, 0, stream>>>(xv_bf, Wv_bf, packed, 1, 128, 0);  // v contiguous

  post_gemm_k<<<8192, 256, 0, stream>>>(v_first, lora8, w0, w2, a0, a2, v0, v2,
                                        k_k, k_a, packed);

  scan_k<<<256, 64, 0, stream>>>(packed);

  post_gn_k<<<8192, 256, 0, stream>>>(packed, lora8, g2, ln_g, ln_b, r_k, og);

  gemm_k<<<gg, 256, 0, stream>>>(og, Wo_bf, out, 0, 0, 0);

  hipMemcpyAsync(out + 16777216, v_first, (size_t)16777216 * 4,
                 hipMemcpyDeviceToDevice, stream);
}